// Round 5
// baseline (4335.997 us; speedup 1.0000x reference)
//
#include <hip/hip_runtime.h>
#include <hip/hip_bf16.h>

// ThinkSortTransformer fused kernel, MI355X (gfx950).
// Inputs f32, output f32. One block per batch element; 20-step scan fused.
// All matmuls are emulated-f32: bf16 hi/lo operand pairs, 3 MFMAs per tile
// (Ah*Bh + Ah*Bl + Al*Bh). Residual/LN/softmax in f32 registers.

typedef unsigned short ushort_t;
using short8  = __attribute__((ext_vector_type(8))) short;
using floatx4 = __attribute__((ext_vector_type(4))) float;

#define MFMA(a,b,c) __builtin_amdgcn_mfma_f32_16x16x32_bf16((a),(b),(c),0,0,0)
#define LD8(base, idx) (*(const short8*)((base) + (idx)))

__device__ __forceinline__ float bf2f(ushort_t u){ return __uint_as_float(((unsigned)u)<<16); }
__device__ __forceinline__ ushort_t f2bf(float f){
  unsigned u = __float_as_uint(f);
  u += 0x7fffu + ((u>>16)&1u);           // round-to-nearest-even
  return (ushort_t)(u>>16);
}
// split-store: hi + lo bf16 (x ~= hi + lo, err <= 2^-17 |x|)
__device__ __forceinline__ void st2(ushort_t* ph, ushort_t* pl, int idx, float x){
  ushort_t h = f2bf(x);
  ph[idx] = h;
  pl[idx] = f2bf(x - bf2f(h));
}
__device__ __forceinline__ short8 zero8(){
  short8 v; v[0]=0;v[1]=0;v[2]=0;v[3]=0;v[4]=0;v[5]=0;v[6]=0;v[7]=0; return v;
}
// exact-GELU via Abramowitz-Stegun 7.1.26 erf approx (|err| <= 1.5e-7)
__device__ __forceinline__ float gelu_f(float x){
  float ax = fabsf(x) * 0.70710678118654752f;
  float t  = 1.0f/(1.0f + 0.3275911f*ax);
  float p  = t*(0.254829592f + t*(-0.284496736f + t*(1.421413741f
             + t*(-1.453152027f + t*1.061405429f))));
  float er = 1.0f - p*__expf(-ax*ax);
  er = copysignf(er, x);
  return 0.5f*x*(1.0f + er);
}

// ws layout (ushort elements):
//   0      WgT_hi  [64][128]
//   8192   WqkvT_hi[192][64]
//   20480  WoutT_hi[64][64]
//   24576  W1T_hi  [256][64]
//   40960  W2T_hi  [64][256]
//   57344  tokbf   [11][64]   (single bf16)
//   58048  + same layout again for _lo copies (weights only)
#define LO_OFS 58048

__global__ void tst_transpose(const float* __restrict__ Wg,
                              const float* __restrict__ Wqkv,
                              const float* __restrict__ Wout,
                              const float* __restrict__ W1,
                              const float* __restrict__ W2,
                              const float* __restrict__ tok,
                              ushort_t* __restrict__ ws){
  int i = blockIdx.x*256 + threadIdx.x;
  float w;
  if (i < 8192){                 // WgT [64][128] <- Wg[128][64]
    int n = i>>7, k = i&127;  w = Wg[k*64+n];
  } else if (i < 20480){         // WqkvT [192][64]
    int j = i-8192; int n = j>>6, k = j&63; w = Wqkv[k*192+n];
  } else if (i < 24576){         // WoutT [64][64]
    int j = i-20480; int n = j>>6, k = j&63; w = Wout[k*64+n];
  } else if (i < 40960){         // W1T [256][64]
    int j = i-24576; int n = j>>6, k = j&63; w = W1[k*256+n];
  } else if (i < 57344){         // W2T [64][256]
    int j = i-40960; int n = j>>8, k = j&255; w = W2[k*64+n];
  } else if (i < 58048){         // tokbf [11][64] (single)
    ws[i] = f2bf(tok[i-57344]);
    return;
  } else return;
  ushort_t hi = f2bf(w);
  ws[i] = hi;
  ws[i + LO_OFS] = f2bf(w - bf2f(hi));
}

// LDS pool offsets (ushort), stride 72 rows
#define HB_H  0
#define HB_L  4608
#define Q_H   9216
#define Q_L   13824
#define K_H   18432
#define K_L   23040
#define VT_H  27648
#define VT_L  32256
#define P_H   36864
#define P_L   41472
#define AT_H  46080
#define AT_L  50688
#define OG_S  AT_H        // og (single) unions with at (disjoint lifetime)
#define HID_H 9216        // [64][264] unions q/k region (dead in FFN)
#define HID_L 27648       // [64][264] unions vT/P region
#define POOLN 55296

// LN over rows; y in regs -> hreg + split hbf store
__device__ __forceinline__ void ln_block(float y[4][4], float hreg[4][4],
    const float* gw, const float* bw, ushort_t* pool,
    float* sh_red, float* sh_red2, int col, int lg, int wv, int lc, int tid)
{
  #pragma unroll
  for (int mt=0;mt<4;++mt)
    #pragma unroll
    for (int r=0;r<4;++r){
      float a = y[mt][r], q = a*a;
      #pragma unroll
      for (int o=1;o<16;o<<=1){ a += __shfl_xor(a,o,16); q += __shfl_xor(q,o,16); }
      if (lc == 0){
        int row = mt*16 + lg*4 + r;
        sh_red[row*8 + wv*2]   = a;
        sh_red[row*8 + wv*2+1] = q;
      }
    }
  __syncthreads();
  if (tid < 64){
    float a = sh_red[tid*8]+sh_red[tid*8+2]+sh_red[tid*8+4]+sh_red[tid*8+6];
    float q = sh_red[tid*8+1]+sh_red[tid*8+3]+sh_red[tid*8+5]+sh_red[tid*8+7];
    float mean = a*(1.f/64.f);
    float var  = fmaxf(q*(1.f/64.f) - mean*mean, 0.f);
    sh_red2[tid*2]   = mean;
    sh_red2[tid*2+1] = rsqrtf(var + 1e-5f);
  }
  __syncthreads();
  float gc = gw[col], bc = bw[col];
  #pragma unroll
  for (int mt=0;mt<4;++mt)
    #pragma unroll
    for (int r=0;r<4;++r){
      int row = mt*16 + lg*4 + r;
      float hn = (y[mt][r] - sh_red2[row*2])*sh_red2[row*2+1]*gc + bc;
      hreg[mt][r] = hn;
      st2(pool + HB_H, pool + HB_L, row*72 + col, hn);
    }
}

__global__ __launch_bounds__(256,1) void tst_main(
    const int* __restrict__ xin, const int* __restrict__ out_pos,
    const float* __restrict__ tok, const float* __restrict__ ope,
    const float* __restrict__ stepe, const float* __restrict__ rel,
    const float* __restrict__ bg, const float* __restrict__ bqkv,
    const float* __restrict__ bout, const float* __restrict__ b1,
    const float* __restrict__ b2,
    const float* __restrict__ ln1g, const float* __restrict__ ln1b,
    const float* __restrict__ ln2g, const float* __restrict__ ln2b,
    const float* __restrict__ lnog, const float* __restrict__ lnob,
    const float* __restrict__ Wp, const float* __restrict__ bp,
    const float* __restrict__ Wv, const float* __restrict__ bv,
    const ushort_t* __restrict__ ws, float* __restrict__ outp)
{
  __shared__ __align__(16) ushort_t pool[POOLN];
  __shared__ float sh_rel[128];
  __shared__ int   sh_x[64];
  __shared__ float sh_red[64*8];
  __shared__ float sh_red2[64*2];

  const int b    = blockIdx.x;
  const int tid  = threadIdx.x;
  const int lane = tid & 63;
  const int wv   = tid >> 6;
  const int lc   = lane & 15;
  const int lg   = lane >> 4;
  const int col  = wv*16 + lc;

  const ushort_t* WgT_h   = ws;
  const ushort_t* WqkvT_h = ws + 8192;
  const ushort_t* WoutT_h = ws + 20480;
  const ushort_t* W1T_h   = ws + 24576;
  const ushort_t* W2T_h   = ws + 40960;
  const ushort_t* tokbf   = ws + 57344;
  const ushort_t* WgT_l   = ws + LO_OFS;
  const ushort_t* WqkvT_l = ws + LO_OFS + 8192;
  const ushort_t* WoutT_l = ws + LO_OFS + 20480;
  const ushort_t* W1T_l   = ws + LO_OFS + 24576;
  const ushort_t* W2T_l   = ws + LO_OFS + 40960;

  if (tid < 64) sh_x[tid] = xin[b*64 + tid];
  if (tid >= 128 && tid < 255) sh_rel[tid-128] = rel[tid-128];
  __syncthreads();

  int op = out_pos[0]; if (op > 63) op = 63; if (op < 0) op = 0;

  float hreg[4][4];
  {
    float opec = ope[op*64 + col];
    #pragma unroll
    for (int mt=0;mt<4;++mt)
      #pragma unroll
      for (int r=0;r<4;++r){
        int row = mt*16 + lg*4 + r;
        float v = tok[sh_x[row]*64 + col] + opec;
        hreg[mt][r] = v;
        st2(pool + HB_H, pool + HB_L, row*72 + col, v);
      }
  }
  __syncthreads();

  for (int step=0; step<20; ++step){
    // ---- stage orig = tokbf[x] (single bf16; |orig|~0.02 -> lo negligible) ----
    {
      int i = tid >> 2, tc = (tid & 3) * 16;
      const ushort_t* src = tokbf + sh_x[i]*64 + tc;
      ushort_t* dst = pool + OG_S + i*72 + tc;
      *(short8*)dst      = *(const short8*)src;
      *(short8*)(dst+8)  = *(const short8*)(src+8);
    }
    __syncthreads();

    // ---- G: gate = sigmoid([h|orig] @ Wg + bg); h = h*(1-g)+orig*g+emb ----
    {
      floatx4 acc[4];
      float bgc = bg[col];
      #pragma unroll
      for (int mt=0;mt<4;++mt){ acc[mt][0]=bgc;acc[mt][1]=bgc;acc[mt][2]=bgc;acc[mt][3]=bgc; }
      #pragma unroll
      for (int kc=0; kc<2; ++kc){      // h half: 3-term split
        int bofs = col*128 + kc*32 + lg*8;
        short8 Bh = LD8(WgT_h, bofs), Bl = LD8(WgT_l, bofs);
        #pragma unroll
        for (int mt=0;mt<4;++mt){
          int aofs = (mt*16+lc)*72 + kc*32 + lg*8;
          short8 Ah = LD8(pool + HB_H, aofs), Al = LD8(pool + HB_L, aofs);
          acc[mt] = MFMA(Ah, Bh, acc[mt]);
          acc[mt] = MFMA(Ah, Bl, acc[mt]);
          acc[mt] = MFMA(Al, Bh, acc[mt]);
        }
      }
      #pragma unroll
      for (int kc=2; kc<4; ++kc){      // orig half: single-term
        int bofs = col*128 + kc*32 + lg*8;
        short8 Bh = LD8(WgT_h, bofs);
        #pragma unroll
        for (int mt=0;mt<4;++mt){
          short8 A = LD8(pool + OG_S, (mt*16+lc)*72 + (kc-2)*32 + lg*8);
          acc[mt] = MFMA(A, Bh, acc[mt]);
        }
      }
      __syncthreads();   // hbf reads done before overwrite
      float embc = stepe[step*64 + col];
      #pragma unroll
      for (int mt=0;mt<4;++mt)
        #pragma unroll
        for (int r=0;r<4;++r){
          int row = mt*16 + lg*4 + r;
          float g = 1.f/(1.f + __expf(-acc[mt][r]));
          float ogv = bf2f(pool[OG_S + row*72 + col]);
          float nh = hreg[mt][r]*(1.f-g) + ogv*g + embc;
          hreg[mt][r] = nh;
          st2(pool + HB_H, pool + HB_L, row*72 + col, nh);
        }
    }
    __syncthreads();

    // ---- QKV: h @ Wqkv + bqkv (split) ----
    #pragma unroll
    for (int p=0;p<3;++p){
      float bqc = bqkv[p*64 + col];
      floatx4 aq[4];
      #pragma unroll
      for (int mt=0;mt<4;++mt){ aq[mt][0]=bqc;aq[mt][1]=bqc;aq[mt][2]=bqc;aq[mt][3]=bqc; }
      #pragma unroll
      for (int kc=0;kc<2;++kc){
        int bofs = (p*64 + col)*64 + kc*32 + lg*8;
        short8 Bh = LD8(WqkvT_h, bofs), Bl = LD8(WqkvT_l, bofs);
        #pragma unroll
        for (int mt=0;mt<4;++mt){
          int aofs = (mt*16+lc)*72 + kc*32 + lg*8;
          short8 Ah = LD8(pool + HB_H, aofs), Al = LD8(pool + HB_L, aofs);
          aq[mt] = MFMA(Ah, Bh, aq[mt]);
          aq[mt] = MFMA(Ah, Bl, aq[mt]);
          aq[mt] = MFMA(Al, Bh, aq[mt]);
        }
      }
      #pragma unroll
      for (int mt=0;mt<4;++mt)
        #pragma unroll
        for (int r=0;r<4;++r){
          int row = mt*16 + lg*4 + r;
          float v = aq[mt][r];
          if (p==0)      st2(pool+Q_H,  pool+Q_L,  row*72 + col, v);
          else if (p==1) st2(pool+K_H,  pool+K_L,  row*72 + col, v);
          else           st2(pool+VT_H, pool+VT_L, col*72 + row, v);
        }
    }
    __syncthreads();

    // ---- attention, head-sequential ----
    for (int hd=0; hd<4; ++hd){
      { // scores = q_h @ k_h^T (K=16 zero-padded, split)
        floatx4 sa[4];
        #pragma unroll
        for (int mt=0;mt<4;++mt){ sa[mt][0]=0;sa[mt][1]=0;sa[mt][2]=0;sa[mt][3]=0; }
        short8 Bh = zero8(), Bl = zero8();
        if (lg < 2){
          int bofs = (16*wv+lc)*72 + hd*16 + lg*8;
          Bh = LD8(pool+K_H, bofs); Bl = LD8(pool+K_L, bofs);
        }
        #pragma unroll
        for (int mt=0;mt<4;++mt){
          short8 Ah = zero8(), Al = zero8();
          if (lg < 2){
            int aofs = (mt*16+lc)*72 + hd*16 + lg*8;
            Ah = LD8(pool+Q_H, aofs); Al = LD8(pool+Q_L, aofs);
          }
          sa[mt] = MFMA(Ah, Bh, sa[mt]);
          sa[mt] = MFMA(Ah, Bl, sa[mt]);
          sa[mt] = MFMA(Al, Bh, sa[mt]);
        }
        #pragma unroll
        for (int mt=0;mt<4;++mt)
          #pragma unroll
          for (int r=0;r<4;++r)
            st2(pool+P_H, pool+P_L, (mt*16+lg*4+r)*72 + 16*wv + lc, sa[mt][r]);
      }
      __syncthreads();
      { // softmax rows (scale + bias), split in-place
        int row = tid >> 2, sub = tid & 3;
        float vals[16]; float mx = -1e30f;
        #pragma unroll
        for (int t=0;t<16;++t){
          int j = sub*16 + t, idx = row*72 + j;
          float s = (bf2f(pool[P_H+idx]) + bf2f(pool[P_L+idx]))*0.25f
                    + sh_rel[row - j + 63];
          vals[t] = s; mx = fmaxf(mx, s);
        }
        mx = fmaxf(mx, __shfl_xor(mx, 1, 4));
        mx = fmaxf(mx, __shfl_xor(mx, 2, 4));
        float sm = 0.f;
        #pragma unroll
        for (int t=0;t<16;++t){ float e = __expf(vals[t]-mx); vals[t]=e; sm += e; }
        sm += __shfl_xor(sm, 1, 4);
        sm += __shfl_xor(sm, 2, 4);
        float inv = 1.f/sm;
        #pragma unroll
        for (int t=0;t<16;++t)
          st2(pool+P_H, pool+P_L, row*72 + sub*16 + t, vals[t]*inv);
      }
      __syncthreads();
      { // attn_h = P @ v_h (split)
        floatx4 pa; pa[0]=0;pa[1]=0;pa[2]=0;pa[3]=0;
        #pragma unroll
        for (int kc=0;kc<2;++kc){
          int aofs = (16*wv + lc)*72 + kc*32 + lg*8;
          int bofs = (hd*16 + lc)*72 + kc*32 + lg*8;
          short8 Ah = LD8(pool+P_H,  aofs), Al = LD8(pool+P_L,  aofs);
          short8 Bh = LD8(pool+VT_H, bofs), Bl = LD8(pool+VT_L, bofs);
          pa = MFMA(Ah, Bh, pa);
          pa = MFMA(Ah, Bl, pa);
          pa = MFMA(Al, Bh, pa);
        }
        #pragma unroll
        for (int r=0;r<4;++r)
          st2(pool+AT_H, pool+AT_L, (16*wv + lg*4 + r)*72 + hd*16 + lc, pa[r]);
      }
      __syncthreads();
    }

    // ---- proj: h = LN1(h + attn @ Wout + bout) (split) ----
    {
      floatx4 pj[4];
      float boc = bout[col];
      #pragma unroll
      for (int mt=0;mt<4;++mt){ pj[mt][0]=boc;pj[mt][1]=boc;pj[mt][2]=boc;pj[mt][3]=boc; }
      #pragma unroll
      for (int kc=0;kc<2;++kc){
        int bofs = col*64 + kc*32 + lg*8;
        short8 Bh = LD8(WoutT_h, bofs), Bl = LD8(WoutT_l, bofs);
        #pragma unroll
        for (int mt=0;mt<4;++mt){
          int aofs = (mt*16+lc)*72 + kc*32 + lg*8;
          short8 Ah = LD8(pool+AT_H, aofs), Al = LD8(pool+AT_L, aofs);
          pj[mt] = MFMA(Ah, Bh, pj[mt]);
          pj[mt] = MFMA(Ah, Bl, pj[mt]);
          pj[mt] = MFMA(Al, Bh, pj[mt]);
        }
      }
      float y[4][4];
      #pragma unroll
      for (int mt=0;mt<4;++mt)
        #pragma unroll
        for (int r=0;r<4;++r) y[mt][r] = hreg[mt][r] + pj[mt][r];
      ln_block(y, hreg, ln1g, ln1b, pool, sh_red, sh_red2, col, lg, wv, lc, tid);
    }
    __syncthreads();

    // ---- FFN1: hid = gelu(h @ W1 + b1) (split in, split out) ----
    #pragma unroll
    for (int pass=0; pass<2; ++pass){
      floatx4 f1[4][2];
      #pragma unroll
      for (int nt=0;nt<2;++nt){
        float b1c = b1[64*wv + (pass*2+nt)*16 + lc];
        #pragma unroll
        for (int mt=0;mt<4;++mt){ f1[mt][nt][0]=b1c;f1[mt][nt][1]=b1c;f1[mt][nt][2]=b1c;f1[mt][nt][3]=b1c; }
      }
      #pragma unroll
      for (int kc=0;kc<2;++kc){
        int b0 = (64*wv + (pass*2+0)*16 + lc)*64 + kc*32 + lg*8;
        int b1o= (64*wv + (pass*2+1)*16 + lc)*64 + kc*32 + lg*8;
        short8 Bh0 = LD8(W1T_h, b0),  Bl0 = LD8(W1T_l, b0);
        short8 Bh1 = LD8(W1T_h, b1o), Bl1 = LD8(W1T_l, b1o);
        #pragma unroll
        for (int mt=0;mt<4;++mt){
          int aofs = (mt*16+lc)*72 + kc*32 + lg*8;
          short8 Ah = LD8(pool + HB_H, aofs), Al = LD8(pool + HB_L, aofs);
          f1[mt][0] = MFMA(Ah, Bh0, f1[mt][0]);
          f1[mt][0] = MFMA(Ah, Bl0, f1[mt][0]);
          f1[mt][0] = MFMA(Al, Bh0, f1[mt][0]);
          f1[mt][1] = MFMA(Ah, Bh1, f1[mt][1]);
          f1[mt][1] = MFMA(Ah, Bl1, f1[mt][1]);
          f1[mt][1] = MFMA(Al, Bh1, f1[mt][1]);
        }
      }
      #pragma unroll
      for (int nt=0;nt<2;++nt)
        #pragma unroll
        for (int mt=0;mt<4;++mt)
          #pragma unroll
          for (int r=0;r<4;++r){
            int row = mt*16 + lg*4 + r;
            int cc  = 64*wv + (pass*2+nt)*16 + lc;
            st2(pool+HID_H, pool+HID_L, row*264 + cc, gelu_f(f1[mt][nt][r]));
          }
    }
    __syncthreads();

    // ---- FFN2: h = LN2(h + hid @ W2 + b2) (split) ----
    {
      floatx4 f2[4];
      float b2c = b2[col];
      #pragma unroll
      for (int mt=0;mt<4;++mt){ f2[mt][0]=b2c;f2[mt][1]=b2c;f2[mt][2]=b2c;f2[mt][3]=b2c; }
      #pragma unroll
      for (int kc=0;kc<8;++kc){
        int bofs = col*256 + kc*32 + lg*8;
        short8 Bh = LD8(W2T_h, bofs), Bl = LD8(W2T_l, bofs);
        #pragma unroll
        for (int mt=0;mt<4;++mt){
          int aofs = (mt*16+lc)*264 + kc*32 + lg*8;
          short8 Ah = LD8(pool+HID_H, aofs), Al = LD8(pool+HID_L, aofs);
          f2[mt] = MFMA(Ah, Bh, f2[mt]);
          f2[mt] = MFMA(Ah, Bl, f2[mt]);
          f2[mt] = MFMA(Al, Bh, f2[mt]);
        }
      }
      float y[4][4];
      #pragma unroll
      for (int mt=0;mt<4;++mt)
        #pragma unroll
        for (int r=0;r<4;++r) y[mt][r] = hreg[mt][r] + f2[mt][r];
      ln_block(y, hreg, ln2g, ln2b, pool, sh_red, sh_red2, col, lg, wv, lc, tid);
    }
    __syncthreads();
  } // steps

  // ---- epilogue: h_out = LN(h, lno); pooled; policy/value ----
  {
    #pragma unroll
    for (int mt=0;mt<4;++mt)
      #pragma unroll
      for (int r=0;r<4;++r){
        float a = hreg[mt][r], q = a*a;
        #pragma unroll
        for (int o=1;o<16;o<<=1){ a += __shfl_xor(a,o,16); q += __shfl_xor(q,o,16); }
        if (lc == 0){
          int row = mt*16 + lg*4 + r;
          sh_red[row*8 + wv*2]   = a;
          sh_red[row*8 + wv*2+1] = q;
        }
      }
    __syncthreads();
    if (tid < 64){
      float a = sh_red[tid*8]+sh_red[tid*8+2]+sh_red[tid*8+4]+sh_red[tid*8+6];
      float q = sh_red[tid*8+1]+sh_red[tid*8+3]+sh_red[tid*8+5]+sh_red[tid*8+7];
      float mean = a*(1.f/64.f);
      float var  = fmaxf(q*(1.f/64.f) - mean*mean, 0.f);
      sh_red2[tid*2]   = mean;
      sh_red2[tid*2+1] = rsqrtf(var + 1e-5f);
    }
    __syncthreads();
    float gc = lnog[col], bc = lnob[col];
    float psum = 0.f;
    #pragma unroll
    for (int mt=0;mt<4;++mt)
      #pragma unroll
      for (int r=0;r<4;++r){
        int row = mt*16 + lg*4 + r;
        float hn = (hreg[mt][r] - sh_red2[row*2])*sh_red2[row*2+1]*gc + bc;
        outp[22528 + (size_t)b*4096 + row*64 + col] = hn;
        psum += hn;
      }
    sh_red[(wv*16+lc)*4 + lg] = psum;
    __syncthreads();
    if (tid < 64){
      float p = sh_red[tid*4] + sh_red[tid*4+1] + sh_red[tid*4+2] + sh_red[tid*4+3];
      sh_red2[tid] = p * (1.f/64.f);
    }
    __syncthreads();
    if (tid < 10){
      float a = bp[tid];
      for (int d2=0; d2<64; ++d2) a += sh_red2[d2]*Wp[d2*10+tid];
      outp[(size_t)b*10 + tid] = a;
    }
    if (tid == 16){
      float a = bv[0];
      for (int d2=0; d2<64; ++d2) a += sh_red2[d2]*Wv[d2];
      outp[20480 + (size_t)b] = a;
    }
  }
}

extern "C" void kernel_launch(void* const* d_in, const int* in_sizes, int n_in,
                              void* d_out, int out_size, void* d_ws, size_t ws_size,
                              hipStream_t stream) {
  const int*   x       = (const int*)d_in[0];
  const int*   out_pos = (const int*)d_in[1];
  const float* tok     = (const float*)d_in[2];
  const float* ope     = (const float*)d_in[3];
  const float* stepe   = (const float*)d_in[4];
  const float* rel     = (const float*)d_in[5];
  const float* Wg      = (const float*)d_in[6];
  const float* bg      = (const float*)d_in[7];
  const float* Wqkv    = (const float*)d_in[8];
  const float* bqkv    = (const float*)d_in[9];
  const float* Wout    = (const float*)d_in[10];
  const float* bout    = (const float*)d_in[11];
  const float* W1      = (const float*)d_in[12];
  const float* b1      = (const float*)d_in[13];
  const float* W2      = (const float*)d_in[14];
  const float* b2      = (const float*)d_in[15];
  const float* ln1g    = (const float*)d_in[16];
  const float* ln1b    = (const float*)d_in[17];
  const float* ln2g    = (const float*)d_in[18];
  const float* ln2b    = (const float*)d_in[19];
  const float* lnog    = (const float*)d_in[20];
  const float* lnob    = (const float*)d_in[21];
  const float* Wp      = (const float*)d_in[22];
  const float* bp      = (const float*)d_in[23];
  const float* Wv      = (const float*)d_in[24];
  const float* bv      = (const float*)d_in[25];
  ushort_t* ws  = (ushort_t*)d_ws;
  float*    out = (float*)d_out;

  tst_transpose<<<227, 256, 0, stream>>>(Wg, Wqkv, Wout, W1, W2, tok, ws);
  tst_main<<<2048, 256, 0, stream>>>(x, out_pos, tok, ope, stepe, rel,
      bg, bqkv, bout, b1, b2, ln1g, ln1b, ln2g, ln2b, lnog, lnob,
      Wp, bp, Wv, bv, ws, out);
}

// Round 6
// 3158.913 us; speedup vs baseline: 1.3726x; 1.3726x over previous
//
#include <hip/hip_runtime.h>
#include <hip/hip_bf16.h>

// ThinkSortTransformer fused kernel, MI355X (gfx950).
// Inputs f32, output f32. One block per batch element; 20-step scan fused.
// Carried state h: bf16 hi/lo pair (emulated-f32). Weights: hi/lo in d_ws.
// Per-step transients (q,k,vT,scores,P,attn,ffn-hidden): single bf16
// (LN-damped each step). 2 blocks/CU (LDS ~77KB).

typedef unsigned short ushort_t;
using short8  = __attribute__((ext_vector_type(8))) short;
using floatx4 = __attribute__((ext_vector_type(4))) float;

#define MFMA(a,b,c) __builtin_amdgcn_mfma_f32_16x16x32_bf16((a),(b),(c),0,0,0)
#define LD8(base, idx) (*(const short8*)((base) + (idx)))

__device__ __forceinline__ float bf2f(ushort_t u){ return __uint_as_float(((unsigned)u)<<16); }
__device__ __forceinline__ ushort_t f2bf(float f){
  unsigned u = __float_as_uint(f);
  u += 0x7fffu + ((u>>16)&1u);           // round-to-nearest-even
  return (ushort_t)(u>>16);
}
// split-store: hi + lo bf16 (x ~= hi + lo, err <= 2^-18 |x|)
__device__ __forceinline__ void st2(ushort_t* ph, ushort_t* pl, int idx, float x){
  ushort_t h = f2bf(x);
  ph[idx] = h;
  pl[idx] = f2bf(x - bf2f(h));
}
__device__ __forceinline__ short8 zero8(){
  short8 v; v[0]=0;v[1]=0;v[2]=0;v[3]=0;v[4]=0;v[5]=0;v[6]=0;v[7]=0; return v;
}
// exact-GELU via Abramowitz-Stegun 7.1.26 erf approx (|err| <= 1.5e-7)
__device__ __forceinline__ float gelu_f(float x){
  float ax = fabsf(x) * 0.70710678118654752f;
  float t  = 1.0f/(1.0f + 0.3275911f*ax);
  float p  = t*(0.254829592f + t*(-0.284496736f + t*(1.421413741f
             + t*(-1.453152027f + t*1.061405429f))));
  float er = 1.0f - p*__expf(-ax*ax);
  er = copysignf(er, x);
  return 0.5f*x*(1.0f + er);
}

// ws layout (ushort): hi block, tokbf, then lo block at +LO_OFS
#define LO_OFS 58048
__global__ void tst_transpose(const float* __restrict__ Wg,
                              const float* __restrict__ Wqkv,
                              const float* __restrict__ Wout,
                              const float* __restrict__ W1,
                              const float* __restrict__ W2,
                              const float* __restrict__ tok,
                              ushort_t* __restrict__ ws){
  int i = blockIdx.x*256 + threadIdx.x;
  float w;
  if (i < 8192){                 // WgT [64][128] <- Wg[128][64]
    int n = i>>7, k = i&127;  w = Wg[k*64+n];
  } else if (i < 20480){         // WqkvT [192][64]
    int j = i-8192; int n = j>>6, k = j&63; w = Wqkv[k*192+n];
  } else if (i < 24576){         // WoutT [64][64]
    int j = i-20480; int n = j>>6, k = j&63; w = Wout[k*64+n];
  } else if (i < 40960){         // W1T [256][64]
    int j = i-24576; int n = j>>6, k = j&63; w = W1[k*256+n];
  } else if (i < 57344){         // W2T [64][256]
    int j = i-40960; int n = j>>8, k = j&255; w = W2[k*64+n];
  } else if (i < 58048){         // tokbf [11][64] (single)
    ws[i] = f2bf(tok[i-57344]);
    return;
  } else return;
  ushort_t hi = f2bf(w);
  ws[i] = hi;
  ws[i + LO_OFS] = f2bf(w - bf2f(hi));
}

// LDS pool offsets (ushort), row stride 72
#define HB_H  0        // h hi   [64][72]
#define HB_L  4608     // h lo   [64][72]
#define OG_S  9216     // orig   [64][72] (persistent, staged once)
#define Q_S   13824    // q      [64][72]
#define K_S   18432    // k      [64][72]
#define VT_S  23040    // vT     [64][72]
#define P_S   27648    // scores/probs [64][72]
#define AT_S  32256    // attn   [64][72]
#define HID_S 13824    // ffn hidden [64][264], unions Q..P (dead in FFN)
#define POOLN 36864

// LN over rows; y in regs -> hreg + split h store
__device__ __forceinline__ void ln_block(float y[4][4], float hreg[4][4],
    const float* gw, const float* bw, ushort_t* pool,
    float* sh_red, float* sh_red2, int col, int lg, int wv, int lc, int tid)
{
  #pragma unroll
  for (int mt=0;mt<4;++mt)
    #pragma unroll
    for (int r=0;r<4;++r){
      float a = y[mt][r], q = a*a;
      #pragma unroll
      for (int o=1;o<16;o<<=1){ a += __shfl_xor(a,o,16); q += __shfl_xor(q,o,16); }
      if (lc == 0){
        int row = mt*16 + lg*4 + r;
        sh_red[row*8 + wv*2]   = a;
        sh_red[row*8 + wv*2+1] = q;
      }
    }
  __syncthreads();
  if (tid < 64){
    float a = sh_red[tid*8]+sh_red[tid*8+2]+sh_red[tid*8+4]+sh_red[tid*8+6];
    float q = sh_red[tid*8+1]+sh_red[tid*8+3]+sh_red[tid*8+5]+sh_red[tid*8+7];
    float mean = a*(1.f/64.f);
    float var  = fmaxf(q*(1.f/64.f) - mean*mean, 0.f);
    sh_red2[tid*2]   = mean;
    sh_red2[tid*2+1] = rsqrtf(var + 1e-5f);
  }
  __syncthreads();
  float gc = gw[col], bc = bw[col];
  #pragma unroll
  for (int mt=0;mt<4;++mt)
    #pragma unroll
    for (int r=0;r<4;++r){
      int row = mt*16 + lg*4 + r;
      float hn = (y[mt][r] - sh_red2[row*2])*sh_red2[row*2+1]*gc + bc;
      hreg[mt][r] = hn;
      st2(pool + HB_H, pool + HB_L, row*72 + col, hn);
    }
}

__global__ __launch_bounds__(256,2) void tst_main(
    const int* __restrict__ xin, const int* __restrict__ out_pos,
    const float* __restrict__ tok, const float* __restrict__ ope,
    const float* __restrict__ stepe, const float* __restrict__ rel,
    const float* __restrict__ bg, const float* __restrict__ bqkv,
    const float* __restrict__ bout, const float* __restrict__ b1,
    const float* __restrict__ b2,
    const float* __restrict__ ln1g, const float* __restrict__ ln1b,
    const float* __restrict__ ln2g, const float* __restrict__ ln2b,
    const float* __restrict__ lnog, const float* __restrict__ lnob,
    const float* __restrict__ Wp, const float* __restrict__ bp,
    const float* __restrict__ Wv, const float* __restrict__ bv,
    const ushort_t* __restrict__ ws, float* __restrict__ outp)
{
  __shared__ __align__(16) ushort_t pool[POOLN];
  __shared__ float sh_rel[128];
  __shared__ int   sh_x[64];
  __shared__ float sh_red[64*8];
  __shared__ float sh_red2[64*2];

  const int b    = blockIdx.x;
  const int tid  = threadIdx.x;
  const int lane = tid & 63;
  const int wv   = tid >> 6;
  const int lc   = lane & 15;
  const int lg   = lane >> 4;
  const int col  = wv*16 + lc;

  const ushort_t* WgT_h   = ws;
  const ushort_t* WqkvT_h = ws + 8192;
  const ushort_t* WoutT_h = ws + 20480;
  const ushort_t* W1T_h   = ws + 24576;
  const ushort_t* W2T_h   = ws + 40960;
  const ushort_t* tokbf   = ws + 57344;
  const ushort_t* WgT_l   = ws + LO_OFS;
  const ushort_t* WqkvT_l = ws + LO_OFS + 8192;
  const ushort_t* WoutT_l = ws + LO_OFS + 20480;
  const ushort_t* W1T_l   = ws + LO_OFS + 24576;
  const ushort_t* W2T_l   = ws + LO_OFS + 40960;

  if (tid < 64) sh_x[tid] = xin[b*64 + tid];
  if (tid >= 128 && tid < 255) sh_rel[tid-128] = rel[tid-128];
  __syncthreads();

  int op = out_pos[0]; if (op > 63) op = 63; if (op < 0) op = 0;

  // stage orig ONCE (step-invariant) + init h
  {
    int i = tid >> 2, tc = (tid & 3) * 16;
    const ushort_t* src = tokbf + sh_x[i]*64 + tc;
    ushort_t* dst = pool + OG_S + i*72 + tc;
    *(short8*)dst      = *(const short8*)src;
    *(short8*)(dst+8)  = *(const short8*)(src+8);
  }
  float hreg[4][4];
  {
    float opec = ope[op*64 + col];
    #pragma unroll
    for (int mt=0;mt<4;++mt)
      #pragma unroll
      for (int r=0;r<4;++r){
        int row = mt*16 + lg*4 + r;
        float v = tok[sh_x[row]*64 + col] + opec;
        hreg[mt][r] = v;
        st2(pool + HB_H, pool + HB_L, row*72 + col, v);
      }
  }
  __syncthreads();

  for (int step=0; step<20; ++step){
    // ---- G: gate = sigmoid([h|orig] @ Wg + bg); h = h*(1-g)+orig*g+emb ----
    {
      floatx4 acc[4];
      float bgc = bg[col];
      #pragma unroll
      for (int mt=0;mt<4;++mt){ acc[mt][0]=bgc;acc[mt][1]=bgc;acc[mt][2]=bgc;acc[mt][3]=bgc; }
      #pragma unroll
      for (int kc=0; kc<2; ++kc){      // h half: 3-term split
        int bofs = col*128 + kc*32 + lg*8;
        short8 Bh = LD8(WgT_h, bofs), Bl = LD8(WgT_l, bofs);
        #pragma unroll
        for (int mt=0;mt<4;++mt){
          int aofs = (mt*16+lc)*72 + kc*32 + lg*8;
          short8 Ah = LD8(pool + HB_H, aofs), Al = LD8(pool + HB_L, aofs);
          acc[mt] = MFMA(Ah, Bh, acc[mt]);
          acc[mt] = MFMA(Ah, Bl, acc[mt]);
          acc[mt] = MFMA(Al, Bh, acc[mt]);
        }
      }
      #pragma unroll
      for (int kc=2; kc<4; ++kc){      // orig half: single-term
        int bofs = col*128 + kc*32 + lg*8;
        short8 Bh = LD8(WgT_h, bofs);
        #pragma unroll
        for (int mt=0;mt<4;++mt){
          short8 A = LD8(pool + OG_S, (mt*16+lc)*72 + (kc-2)*32 + lg*8);
          acc[mt] = MFMA(A, Bh, acc[mt]);
        }
      }
      __syncthreads();   // h reads done before overwrite
      float embc = stepe[step*64 + col];
      #pragma unroll
      for (int mt=0;mt<4;++mt)
        #pragma unroll
        for (int r=0;r<4;++r){
          int row = mt*16 + lg*4 + r;
          float g = 1.f/(1.f + __expf(-acc[mt][r]));
          float ogv = bf2f(pool[OG_S + row*72 + col]);
          float nh = hreg[mt][r]*(1.f-g) + ogv*g + embc;
          hreg[mt][r] = nh;
          st2(pool + HB_H, pool + HB_L, row*72 + col, nh);
        }
    }
    __syncthreads();

    // ---- QKV: h @ Wqkv + bqkv (3-term); outputs single bf16 ----
    #pragma unroll
    for (int p=0;p<3;++p){
      float bqc = bqkv[p*64 + col];
      floatx4 aq[4];
      #pragma unroll
      for (int mt=0;mt<4;++mt){ aq[mt][0]=bqc;aq[mt][1]=bqc;aq[mt][2]=bqc;aq[mt][3]=bqc; }
      #pragma unroll
      for (int kc=0;kc<2;++kc){
        int bofs = (p*64 + col)*64 + kc*32 + lg*8;
        short8 Bh = LD8(WqkvT_h, bofs), Bl = LD8(WqkvT_l, bofs);
        #pragma unroll
        for (int mt=0;mt<4;++mt){
          int aofs = (mt*16+lc)*72 + kc*32 + lg*8;
          short8 Ah = LD8(pool + HB_H, aofs), Al = LD8(pool + HB_L, aofs);
          aq[mt] = MFMA(Ah, Bh, aq[mt]);
          aq[mt] = MFMA(Ah, Bl, aq[mt]);
          aq[mt] = MFMA(Al, Bh, aq[mt]);
        }
      }
      #pragma unroll
      for (int mt=0;mt<4;++mt)
        #pragma unroll
        for (int r=0;r<4;++r){
          int row = mt*16 + lg*4 + r;
          ushort_t v = f2bf(aq[mt][r]);
          if (p==0)      pool[Q_S  + row*72 + col] = v;
          else if (p==1) pool[K_S  + row*72 + col] = v;
          else           pool[VT_S + col*72 + row] = v;
        }
    }
    __syncthreads();

    // ---- attention, head-sequential ----
    for (int hd=0; hd<4; ++hd){
      { // scores = q_h @ k_h^T (K=16 zero-padded), single-term
        floatx4 sa[4];
        #pragma unroll
        for (int mt=0;mt<4;++mt){ sa[mt][0]=0;sa[mt][1]=0;sa[mt][2]=0;sa[mt][3]=0; }
        short8 Bh = zero8();
        if (lg < 2) Bh = LD8(pool+K_S, (16*wv+lc)*72 + hd*16 + lg*8);
        #pragma unroll
        for (int mt=0;mt<4;++mt){
          short8 Ah = zero8();
          if (lg < 2) Ah = LD8(pool+Q_S, (mt*16+lc)*72 + hd*16 + lg*8);
          sa[mt] = MFMA(Ah, Bh, sa[mt]);
        }
        #pragma unroll
        for (int mt=0;mt<4;++mt)
          #pragma unroll
          for (int r=0;r<4;++r)
            pool[P_S + (mt*16+lg*4+r)*72 + 16*wv + lc] = f2bf(sa[mt][r]);
      }
      __syncthreads();
      { // softmax rows (scale + bias); packed dword writes
        int row = tid >> 2, sub = tid & 3;
        float vals[16]; float mx = -1e30f;
        #pragma unroll
        for (int t=0;t<16;++t){
          int j = sub*16 + t;
          float s = bf2f(pool[P_S + row*72 + j])*0.25f + sh_rel[row - j + 63];
          vals[t] = s; mx = fmaxf(mx, s);
        }
        mx = fmaxf(mx, __shfl_xor(mx, 1, 4));
        mx = fmaxf(mx, __shfl_xor(mx, 2, 4));
        float sm = 0.f;
        #pragma unroll
        for (int t=0;t<16;++t){ float e = __expf(vals[t]-mx); vals[t]=e; sm += e; }
        sm += __shfl_xor(sm, 1, 4);
        sm += __shfl_xor(sm, 2, 4);
        float inv = 1.f/sm;
        unsigned* pw = (unsigned*)(pool + P_S + row*72 + sub*16);
        #pragma unroll
        for (int t=0;t<8;++t){
          unsigned lo = f2bf(vals[2*t]*inv);
          unsigned hi = f2bf(vals[2*t+1]*inv);
          pw[t] = lo | (hi<<16);
        }
      }
      __syncthreads();
      { // attn_h = P @ v_h, single-term
        floatx4 pa; pa[0]=0;pa[1]=0;pa[2]=0;pa[3]=0;
        #pragma unroll
        for (int kc=0;kc<2;++kc){
          short8 Ah = LD8(pool+P_S,  (16*wv + lc)*72 + kc*32 + lg*8);
          short8 Bh = LD8(pool+VT_S, (hd*16 + lc)*72 + kc*32 + lg*8);
          pa = MFMA(Ah, Bh, pa);
        }
        #pragma unroll
        for (int r=0;r<4;++r)
          pool[AT_S + (16*wv + lg*4 + r)*72 + hd*16 + lc] = f2bf(pa[r]);
      }
      __syncthreads();
    }

    // ---- proj: h = LN1(h + attn @ Wout + bout), 2-term ----
    {
      floatx4 pj[4];
      float boc = bout[col];
      #pragma unroll
      for (int mt=0;mt<4;++mt){ pj[mt][0]=boc;pj[mt][1]=boc;pj[mt][2]=boc;pj[mt][3]=boc; }
      #pragma unroll
      for (int kc=0;kc<2;++kc){
        int bofs = col*64 + kc*32 + lg*8;
        short8 Bh = LD8(WoutT_h, bofs), Bl = LD8(WoutT_l, bofs);
        #pragma unroll
        for (int mt=0;mt<4;++mt){
          short8 A = LD8(pool+AT_S, (mt*16+lc)*72 + kc*32 + lg*8);
          pj[mt] = MFMA(A, Bh, pj[mt]);
          pj[mt] = MFMA(A, Bl, pj[mt]);
        }
      }
      float y[4][4];
      #pragma unroll
      for (int mt=0;mt<4;++mt)
        #pragma unroll
        for (int r=0;r<4;++r) y[mt][r] = hreg[mt][r] + pj[mt][r];
      ln_block(y, hreg, ln1g, ln1b, pool, sh_red, sh_red2, col, lg, wv, lc, tid);
    }
    __syncthreads();

    // ---- FFN1: hid = gelu(h @ W1 + b1), 3-term in, single out ----
    #pragma unroll
    for (int pass=0; pass<2; ++pass){
      floatx4 f1[4][2];
      #pragma unroll
      for (int nt=0;nt<2;++nt){
        float b1c = b1[64*wv + (pass*2+nt)*16 + lc];
        #pragma unroll
        for (int mt=0;mt<4;++mt){ f1[mt][nt][0]=b1c;f1[mt][nt][1]=b1c;f1[mt][nt][2]=b1c;f1[mt][nt][3]=b1c; }
      }
      #pragma unroll
      for (int kc=0;kc<2;++kc){
        int b0 = (64*wv + (pass*2+0)*16 + lc)*64 + kc*32 + lg*8;
        int b1o= (64*wv + (pass*2+1)*16 + lc)*64 + kc*32 + lg*8;
        short8 Bh0 = LD8(W1T_h, b0),  Bl0 = LD8(W1T_l, b0);
        short8 Bh1 = LD8(W1T_h, b1o), Bl1 = LD8(W1T_l, b1o);
        #pragma unroll
        for (int mt=0;mt<4;++mt){
          int aofs = (mt*16+lc)*72 + kc*32 + lg*8;
          short8 Ah = LD8(pool + HB_H, aofs), Al = LD8(pool + HB_L, aofs);
          f1[mt][0] = MFMA(Ah, Bh0, f1[mt][0]);
          f1[mt][0] = MFMA(Ah, Bl0, f1[mt][0]);
          f1[mt][0] = MFMA(Al, Bh0, f1[mt][0]);
          f1[mt][1] = MFMA(Ah, Bh1, f1[mt][1]);
          f1[mt][1] = MFMA(Ah, Bl1, f1[mt][1]);
          f1[mt][1] = MFMA(Al, Bh1, f1[mt][1]);
        }
      }
      __syncthreads();  // HID unions Q..P; ensure attn-phase reads done (pass 0 only matters)
      #pragma unroll
      for (int nt=0;nt<2;++nt)
        #pragma unroll
        for (int mt=0;mt<4;++mt)
          #pragma unroll
          for (int r=0;r<4;++r){
            int row = mt*16 + lg*4 + r;
            int cc  = 64*wv + (pass*2+nt)*16 + lc;
            pool[HID_S + row*264 + cc] = f2bf(gelu_f(f1[mt][nt][r]));
          }
    }
    __syncthreads();

    // ---- FFN2: h = LN2(h + hid @ W2 + b2), 2-term ----
    {
      floatx4 f2[4];
      float b2c = b2[col];
      #pragma unroll
      for (int mt=0;mt<4;++mt){ f2[mt][0]=b2c;f2[mt][1]=b2c;f2[mt][2]=b2c;f2[mt][3]=b2c; }
      #pragma unroll
      for (int kc=0;kc<8;++kc){
        int bofs = col*256 + kc*32 + lg*8;
        short8 Bh = LD8(W2T_h, bofs), Bl = LD8(W2T_l, bofs);
        #pragma unroll
        for (int mt=0;mt<4;++mt){
          short8 A = LD8(pool+HID_S, (mt*16+lc)*264 + kc*32 + lg*8);
          f2[mt] = MFMA(A, Bh, f2[mt]);
          f2[mt] = MFMA(A, Bl, f2[mt]);
        }
      }
      float y[4][4];
      #pragma unroll
      for (int mt=0;mt<4;++mt)
        #pragma unroll
        for (int r=0;r<4;++r) y[mt][r] = hreg[mt][r] + f2[mt][r];
      ln_block(y, hreg, ln2g, ln2b, pool, sh_red, sh_red2, col, lg, wv, lc, tid);
    }
    __syncthreads();
  } // steps

  // ---- epilogue: h_out = LN(h, lno); pooled; policy/value ----
  {
    #pragma unroll
    for (int mt=0;mt<4;++mt)
      #pragma unroll
      for (int r=0;r<4;++r){
        float a = hreg[mt][r], q = a*a;
        #pragma unroll
        for (int o=1;o<16;o<<=1){ a += __shfl_xor(a,o,16); q += __shfl_xor(q,o,16); }
        if (lc == 0){
          int row = mt*16 + lg*4 + r;
          sh_red[row*8 + wv*2]   = a;
          sh_red[row*8 + wv*2+1] = q;
        }
      }
    __syncthreads();
    if (tid < 64){
      float a = sh_red[tid*8]+sh_red[tid*8+2]+sh_red[tid*8+4]+sh_red[tid*8+6];
      float q = sh_red[tid*8+1]+sh_red[tid*8+3]+sh_red[tid*8+5]+sh_red[tid*8+7];
      float mean = a*(1.f/64.f);
      float var  = fmaxf(q*(1.f/64.f) - mean*mean, 0.f);
      sh_red2[tid*2]   = mean;
      sh_red2[tid*2+1] = rsqrtf(var + 1e-5f);
    }
    __syncthreads();
    float gc = lnog[col], bc = lnob[col];
    float psum = 0.f;
    #pragma unroll
    for (int mt=0;mt<4;++mt)
      #pragma unroll
      for (int r=0;r<4;++r){
        int row = mt*16 + lg*4 + r;
        float hn = (hreg[mt][r] - sh_red2[row*2])*sh_red2[row*2+1]*gc + bc;
        outp[22528 + (size_t)b*4096 + row*64 + col] = hn;
        psum += hn;
      }
    sh_red[(wv*16+lc)*4 + lg] = psum;
    __syncthreads();
    if (tid < 64){
      float p = sh_red[tid*4] + sh_red[tid*4+1] + sh_red[tid*4+2] + sh_red[tid*4+3];
      sh_red2[tid] = p * (1.f/64.f);
    }
    __syncthreads();
    if (tid < 10){
      float a = bp[tid];
      for (int d2=0; d2<64; ++d2) a += sh_red2[d2]*Wp[d2*10+tid];
      outp[(size_t)b*10 + tid] = a;
    }
    if (tid == 16){
      float a = bv[0];
      for (int d2=0; d2<64; ++d2) a += sh_red2[d2]*Wv[d2];
      outp[20480 + (size_t)b] = a;
    }
  }
}

extern "C" void kernel_launch(void* const* d_in, const int* in_sizes, int n_in,
                              void* d_out, int out_size, void* d_ws, size_t ws_size,
                              hipStream_t stream) {
  const int*   x       = (const int*)d_in[0];
  const int*   out_pos = (const int*)d_in[1];
  const float* tok     = (const float*)d_in[2];
  const float* ope     = (const float*)d_in[3];
  const float* stepe   = (const float*)d_in[4];
  const float* rel     = (const float*)d_in[5];
  const float* Wg      = (const float*)d_in[6];
  const float* bg      = (const float*)d_in[7];
  const float* Wqkv    = (const float*)d_in[8];
  const float* bqkv    = (const float*)d_in[9];
  const float* Wout    = (const float*)d_in[10];
  const float* bout    = (const float*)d_in[11];
  const float* W1      = (const float*)d_in[12];
  const float* b1      = (const float*)d_in[13];
  const float* W2      = (const float*)d_in[14];
  const float* b2      = (const float*)d_in[15];
  const float* ln1g    = (const float*)d_in[16];
  const float* ln1b    = (const float*)d_in[17];
  const float* ln2g    = (const float*)d_in[18];
  const float* ln2b    = (const float*)d_in[19];
  const float* lnog    = (const float*)d_in[20];
  const float* lnob    = (const float*)d_in[21];
  const float* Wp      = (const float*)d_in[22];
  const float* bp      = (const float*)d_in[23];
  const float* Wv      = (const float*)d_in[24];
  const float* bv      = (const float*)d_in[25];
  ushort_t* ws  = (ushort_t*)d_ws;
  float*    out = (float*)d_out;

  tst_transpose<<<227, 256, 0, stream>>>(Wg, Wqkv, Wout, W1, W2, tok, ws);
  tst_main<<<2048, 256, 0, stream>>>(x, out_pos, tok, ope, stepe, rel,
      bg, bqkv, bout, b1, b2, ln1g, ln1b, ln2g, ln2b, lnog, lnob,
      Wp, bp, Wv, bv, ws, out);
}